// Round 12
// baseline (45.828 us; speedup 1.0000x reference)
//
#include <hip/hip_runtime.h>
#include <hip/hip_bf16.h>
#include <cstdint>

#define NN 8192
#define DD 512
#define NC 128      // number of classes

typedef unsigned short u16;
typedef __attribute__((ext_vector_type(8))) short short8;
typedef __attribute__((ext_vector_type(4))) float f32x4;

#define AS1 __attribute__((address_space(1)))
#define AS3 __attribute__((address_space(3)))

// workspace layout (bytes)
#define ND_OFF   ((size_t)0)                      // fp32 neg_dist: NN*4
#define ACC_OFF  (ND_OFF + (size_t)NN*4)          // total(f32)@+0, cnt(int)@+4, done(int)@+8
#define CC_OFF   (ACC_OFF + 64)                   // class counts: NC*4
#define POS_OFF  (CC_OFF + 1024)                  // ordered member positions: NC*128*4

// ---- K1: per-class ordered member positions + acc zeroing ----------------
// NO atomics in this kernel -> plain-store zeroing of the accumulator line
// is flushed at kernel end, before k_cls's atomics touch it (r9-verified).
__global__ __launch_bounds__(256) void k_pos(const int* __restrict__ labels,
    int* __restrict__ cc, int* __restrict__ pos, int* __restrict__ accz) {
  const int c = blockIdx.x;
  const int wid = threadIdx.x >> 6, lane = threadIdx.x & 63;
  if (c == 0 && threadIdx.x < 16) accz[threadIdx.x] = 0;
  __shared__ int wcnt[4], woff[4];
  const int base0 = wid * 2048;
  int cw = 0;
  for (int b = 0; b < 2048; b += 64)       // pass 1: count
    cw += __popcll(__ballot(labels[base0 + b + lane] == c));
  if (lane == 0) wcnt[wid] = cw;
  __syncthreads();
  if (threadIdx.x == 0) {
    int o = 0;
    #pragma unroll
    for (int w = 0; w < 4; ++w) { woff[w] = o; o += wcnt[w]; }
    cc[c] = o;
  }
  __syncthreads();
  int off = woff[wid];
  for (int b = 0; b < 2048; b += 64) {     // pass 2: emit (ascending order)
    const int idx = base0 + b + lane;
    const int hit = (labels[idx] == c);
    const unsigned long long m = __ballot(hit);
    if (hit) pos[c * 128 + off + __popcll(m & ((1ull << lane) - 1ull))] = idx;
    off += __popcll(m);
  }
  __syncthreads();
  const int nc = cc[c];
  for (int t = nc + threadIdx.x; t < 128; t += 256) pos[c * 128 + t] = 0; // pad
}

// ---- K2: k-th-negative (ballot rank) + fp32 neg_dist (1 wave/anchor) -----
// Self-contained: sq_i, sq_j, dot all from the same fp32 row reads.
__global__ __launch_bounds__(256) void k_neg(const float* __restrict__ F,
    const int* __restrict__ labels, const float* __restrict__ negu,
    const int* __restrict__ cc, const int* __restrict__ pos,
    float* __restrict__ nd) {
  const int wid = threadIdx.x >> 6, lane = threadIdx.x & 63;
  const int i = blockIdx.x * 4 + wid;
  const int c = labels[i];
  const int nc = cc[c];
  const int n_neg = NN - nc;
  if (n_neg <= 0) { if (lane == 0) nd[i] = __builtin_inff(); return; }
  int k = (int)floorf(negu[i] * (float)n_neg);  // exact fp32 replica of reference
  k = k < 0 ? 0 : (k > n_neg - 1 ? n_neg - 1 : k);
  // rank: pos ascending => pos[t]-t non-decreasing; t* = #{t: pos[t]-t <= k}
  const int* pc = pos + c * 128;
  const int p0 = pc[lane], p1 = pc[64 + lane];
  const int t = __popcll(__ballot((lane < nc) && (p0 - lane <= k)))
              + __popcll(__ballot((64 + lane < nc) && (p1 - (64 + lane) <= k)));
  const int j = k + t;
  const float* fi = F + (size_t)i * DD + lane * 8;
  const float* fj = F + (size_t)j * DD + lane * 8;
  float4 a0 = *(const float4*)fi, a1 = *(const float4*)(fi + 4);
  float4 b0 = *(const float4*)fj, b1 = *(const float4*)(fj + 4);
  float d  = a0.x*b0.x + a0.y*b0.y + a0.z*b0.z + a0.w*b0.w
           + a1.x*b1.x + a1.y*b1.y + a1.z*b1.z + a1.w*b1.w;
  float si = a0.x*a0.x + a0.y*a0.y + a0.z*a0.z + a0.w*a0.w
           + a1.x*a1.x + a1.y*a1.y + a1.z*a1.z + a1.w*a1.w;
  float sj = b0.x*b0.x + b0.y*b0.y + b0.z*b0.z + b0.w*b0.w
           + b1.x*b1.x + b1.y*b1.y + b1.z*b1.z + b1.w*b1.w;
  #pragma unroll
  for (int o = 32; o; o >>= 1) {
    d += __shfl_xor(d, o); si += __shfl_xor(si, o); sj += __shfl_xor(sj, o);
  }
  if (lane == 0) nd[i] = sqrtf(fmaxf(si + sj - 2.0f * d, 1e-11f));
}

// ---- K3: per-class Gram, M-SPLIT 2 blocks/class, fp32 reg-staging --------
// Stages fp32 F rows, converts to bf16 in-register (RNE), ds_writes in the
// swizzled layout (granule lane^(row&7)); per-row sq computed from the same
// registers (bit-identical decomposition to the old k_prep). One barrier,
// then the verified MFMA core + hinge epilogue. Atomics-only accumulators.
__global__ __launch_bounds__(256) void k_cls(const float* __restrict__ F,
    const float* __restrict__ nd, const int* __restrict__ cc,
    const int* __restrict__ pos, float* __restrict__ accf,
    float* __restrict__ out) {
  const int c = blockIdx.x >> 1, half = blockIdx.x & 1;
  __shared__ __align__(16) u16 P[128 * 512];     // 128 KB: full class tile
  __shared__ int posc[128];
  __shared__ float sqc[128], ndc[128];
  __shared__ float red[4];
  const int tid = threadIdx.x, wid = tid >> 6, lane = tid & 63;
  const int nc = cc[c];
  if (tid < 128) posc[tid] = pos[c * 128 + tid];
  __syncthreads();
  if (nc >= 2 && half * 64 < nc) {               // uniform branch per block
    const int wr = half, wc = wid;               // wave grid: 1 x 4
    const int r16 = lane & 15, gg = lane >> 4;

    if (tid < 128) ndc[tid] = nd[posc[tid]];     // global gather (128 values)

    // stage: wave wid covers rows wid*32..+31. lane = one 16B bf16 granule:
    // reads 32B fp32, converts, writes LDS granule lane^(row&7).
    #pragma unroll 4
    for (int s = 0; s < 32; ++s) {
      const int row = wid * 32 + s;
      const float* fr = F + (size_t)posc[row] * DD + lane * 8;
      float4 v0 = *(const float4*)fr;
      float4 v1 = *(const float4*)(fr + 4);
      float sp = v0.x*v0.x + v0.y*v0.y + v0.z*v0.z + v0.w*v0.w
               + v1.x*v1.x + v1.y*v1.y + v1.z*v1.z + v1.w*v1.w;
      #pragma unroll
      for (int o = 32; o; o >>= 1) sp += __shfl_xor(sp, o);
      if (lane == 0) sqc[row] = sp;
      float t[8] = {v0.x, v0.y, v0.z, v0.w, v1.x, v1.y, v1.z, v1.w};
      unsigned p[8];
      #pragma unroll
      for (int e = 0; e < 8; ++e) {              // RNE fp32->bf16
        unsigned b = __float_as_uint(t[e]);
        b += 0x7fffu + ((b >> 16) & 1u);
        p[e] = b >> 16;
      }
      uint4 w;
      w.x = p[0] | (p[1] << 16); w.y = p[2] | (p[3] << 16);
      w.z = p[4] | (p[5] << 16); w.w = p[6] | (p[7] << 16);
      *(uint4*)&P[row * 512 + ((lane ^ (row & 7)) << 3)] = w;
    }

    f32x4 acc[4][2];
    #pragma unroll
    for (int m = 0; m < 4; ++m)
      #pragma unroll
      for (int n = 0; n < 2; ++n)
        #pragma unroll
        for (int q = 0; q < 4; ++q) acc[m][n][q] = 0.0f;

    __syncthreads();                             // staging + sqc/ndc done
    #pragma unroll 4
    for (int t = 0; t < 16; ++t) {               // K = 16 x 32
      short8 af[4], bf[2];
      #pragma unroll
      for (int m = 0; m < 4; ++m) {
        const int row = wr * 64 + m * 16 + r16;
        const int gl = (t * 4 + gg) ^ (row & 7);
        af[m] = *(const short8*)&P[row * 512 + gl * 8];
      }
      #pragma unroll
      for (int n = 0; n < 2; ++n) {
        const int row = wc * 32 + n * 16 + r16;
        const int gl = (t * 4 + gg) ^ (row & 7);
        bf[n] = *(const short8*)&P[row * 512 + gl * 8];
      }
      #pragma unroll
      for (int m = 0; m < 4; ++m)
        #pragma unroll
        for (int n = 0; n < 2; ++n)
          acc[m][n] = __builtin_amdgcn_mfma_f32_16x16x32_bf16(af[m], bf[n], acc[m][n], 0, 0, 0);
    }

    // epilogue: hinge over valid (mi != nj, both < nc) ordered pairs
    float lsum = 0.0f;
    int njv[2]; float sqj[2];
    #pragma unroll
    for (int n = 0; n < 2; ++n) {
      const int nj = wc * 32 + n * 16 + r16;
      njv[n] = nj; sqj[n] = sqc[nj];
    }
    #pragma unroll
    for (int m = 0; m < 4; ++m) {
      #pragma unroll
      for (int q = 0; q < 4; ++q) {
        const int mi = wr * 64 + m * 16 + gg * 4 + q;   // C/D: row=(lane>>4)*4+q
        const float sqi = sqc[mi], ndi = ndc[mi];
        const bool vi = mi < nc;
        #pragma unroll
        for (int n = 0; n < 2; ++n) {
          const float g = acc[m][n][q];
          const float dist = sqrtf(fmaxf(sqi + sqj[n] - 2.0f * g, 1e-11f));
          if (vi & (njv[n] < nc) & (mi != njv[n]))
            lsum += fmaxf(1.0f + dist - ndi, 0.0f);     // nd=inf -> 0 automatically
        }
      }
    }
    #pragma unroll
    for (int o = 32; o; o >>= 1) lsum += __shfl_xor(lsum, o);
    if (lane == 0) red[wid] = lsum;
    __syncthreads();
    if (tid == 0) atomicAdd(accf, red[0] + red[1] + red[2] + red[3]);
  }
  // pair-count (half 0 only) + last-block finalize (atomics only)
  if (tid == 0) {
    int* cnt  = (int*)accf + 1;
    int* done = (int*)accf + 2;
    if (half == 0 && nc < NN) atomicAdd(cnt, nc * (nc - 1));
    __threadfence();
    if (atomicAdd(done, 1) == 2 * NC - 1) {
      const float tot = atomicAdd(accf, 0.0f);    // atomic read
      const int n = atomicAdd(cnt, 0);            // atomic read
      out[0] = tot / (float)n;
    }
  }
}

extern "C" void kernel_launch(void* const* d_in, const int* in_sizes, int n_in,
                              void* d_out, int out_size, void* d_ws, size_t ws_size,
                              hipStream_t stream) {
  const float* F = (const float*)d_in[0];
  const int* labels = (const int*)d_in[1];   // harness materializes integers as int32
  const float* negu = (const float*)d_in[2];
  char* ws = (char*)d_ws;
  float* nd    = (float*)(ws + ND_OFF);
  float* accf  = (float*)(ws + ACC_OFF);
  int*   cc    = (int*)(ws + CC_OFF);
  int*   pos   = (int*)(ws + POS_OFF);

  k_pos<<<NC,     256, 0, stream>>>(labels, cc, pos, (int*)accf);
  k_neg<<<NN / 4, 256, 0, stream>>>(F, labels, negu, cc, pos, nd);
  k_cls<<<2 * NC, 256, 0, stream>>>(F, nd, cc, pos, accf, (float*)d_out);
}

// Round 13
// 34.306 us; speedup vs baseline: 1.3358x; 1.3358x over previous
//
#include <hip/hip_runtime.h>
#include <hip/hip_bf16.h>
#include <cstdint>

#define NN 8192
#define DD 512
#define NC 128      // number of classes

typedef unsigned short u16;
typedef __attribute__((ext_vector_type(8))) short short8;
typedef __attribute__((ext_vector_type(4))) float f32x4;

#define AS1 __attribute__((address_space(1)))
#define AS3 __attribute__((address_space(3)))

// workspace layout (bytes)
#define FB_OFF   ((size_t)0)                      // bf16 features: NN*DD*2 = 8 MB
#define SQ_OFF   (FB_OFF + (size_t)NN*DD*2)       // fp32 sq norms: NN*4
#define ND_OFF   (SQ_OFF + (size_t)NN*4)          // fp32 neg_dist: NN*4
#define ACC_OFF  (ND_OFF + (size_t)NN*4)          // total(f32)@+0, cnt(int)@+4, done(int)@+8
#define CC_OFF   (ACC_OFF + 64)                   // class counts: NC*4
#define POS_OFF  (CC_OFF + 1024)                  // ordered member positions: NC*128*4

// ---- K1: per-class ordered member positions + acc zeroing ----------------
// NO atomics in this kernel -> plain-store zeroing of the accumulator line
// is flushed at kernel end, before k_cls's atomics touch it (r9-verified).
__global__ __launch_bounds__(256) void k_pos(const int* __restrict__ labels,
    int* __restrict__ cc, int* __restrict__ pos, int* __restrict__ accz) {
  const int c = blockIdx.x;
  const int wid = threadIdx.x >> 6, lane = threadIdx.x & 63;
  if (c == 0 && threadIdx.x < 16) accz[threadIdx.x] = 0;
  __shared__ int wcnt[4], woff[4];
  const int base0 = wid * 2048;
  int cw = 0;
  for (int b = 0; b < 2048; b += 64)       // pass 1: count
    cw += __popcll(__ballot(labels[base0 + b + lane] == c));
  if (lane == 0) wcnt[wid] = cw;
  __syncthreads();
  if (threadIdx.x == 0) {
    int o = 0;
    #pragma unroll
    for (int w = 0; w < 4; ++w) { woff[w] = o; o += wcnt[w]; }
    cc[c] = o;
  }
  __syncthreads();
  int off = woff[wid];
  for (int b = 0; b < 2048; b += 64) {     // pass 2: emit (ascending order)
    const int idx = base0 + b + lane;
    const int hit = (labels[idx] == c);
    const unsigned long long m = __ballot(hit);
    if (hit) pos[c * 128 + off + __popcll(m & ((1ull << lane) - 1ull))] = idx;
    off += __popcll(m);
  }
  __syncthreads();
  const int nc = cc[c];
  for (int t = nc + threadIdx.x; t < 128; t += 256) pos[c * 128 + t] = 0; // pad
}

// ---- K2: fused {prep: sq + bf16 cast} | {neg: k-th negative + fp32 nd} ---
// blocks 0..2047: prep (reads F only; writes Fb, sq).
// blocks 2048..4095: neg (reads F, labels, negu, cc, pos; writes nd).
// Halves are data-independent -> overlap in one dispatch. No atomics.
__global__ __launch_bounds__(256) void k_pn(const float* __restrict__ F,
    const int* __restrict__ labels, const float* __restrict__ negu,
    const int* __restrict__ cc, const int* __restrict__ pos,
    u16* __restrict__ Fb, float* __restrict__ sq, float* __restrict__ nd) {
  const int wid = threadIdx.x >> 6, lane = threadIdx.x & 63;
  if (blockIdx.x < 2048) {               // ---------------- prep half
    const int row = blockIdx.x * 4 + wid;
    const float* fr = F + (size_t)row * DD + lane * 8;
    float4 v0 = *(const float4*)fr;
    float4 v1 = *(const float4*)(fr + 4);
    float s = v0.x*v0.x + v0.y*v0.y + v0.z*v0.z + v0.w*v0.w
            + v1.x*v1.x + v1.y*v1.y + v1.z*v1.z + v1.w*v1.w;
    #pragma unroll
    for (int o = 32; o; o >>= 1) s += __shfl_xor(s, o);
    float t[8] = {v0.x, v0.y, v0.z, v0.w, v1.x, v1.y, v1.z, v1.w};
    unsigned p[8];
    #pragma unroll
    for (int e = 0; e < 8; ++e) {   // RNE fp32->bf16
      unsigned b = __float_as_uint(t[e]);
      b += 0x7fffu + ((b >> 16) & 1u);
      p[e] = b >> 16;
    }
    uint4 w;
    w.x = p[0] | (p[1] << 16); w.y = p[2] | (p[3] << 16);
    w.z = p[4] | (p[5] << 16); w.w = p[6] | (p[7] << 16);
    *(uint4*)(Fb + (size_t)row * DD + lane * 8) = w;
    if (lane == 0) sq[row] = s;
  } else {                               // ---------------- neg half
    const int i = (blockIdx.x - 2048) * 4 + wid;
    const int c = labels[i];
    const int nc = cc[c];
    const int n_neg = NN - nc;
    if (n_neg <= 0) { if (lane == 0) nd[i] = __builtin_inff(); return; }
    int k = (int)floorf(negu[i] * (float)n_neg);  // exact fp32 replica of ref
    k = k < 0 ? 0 : (k > n_neg - 1 ? n_neg - 1 : k);
    // rank: pos ascending => pos[t]-t non-decreasing; t* = #{t: pos[t]-t <= k}
    const int* pc = pos + c * 128;
    const int p0 = pc[lane], p1 = pc[64 + lane];
    const int t = __popcll(__ballot((lane < nc) && (p0 - lane <= k)))
                + __popcll(__ballot((64 + lane < nc) && (p1 - (64 + lane) <= k)));
    const int j = k + t;
    const float* fi = F + (size_t)i * DD + lane * 8;
    const float* fj = F + (size_t)j * DD + lane * 8;
    float4 a0 = *(const float4*)fi, a1 = *(const float4*)(fi + 4);
    float4 b0 = *(const float4*)fj, b1 = *(const float4*)(fj + 4);
    float d  = a0.x*b0.x + a0.y*b0.y + a0.z*b0.z + a0.w*b0.w
             + a1.x*b1.x + a1.y*b1.y + a1.z*b1.z + a1.w*b1.w;
    float si = a0.x*a0.x + a0.y*a0.y + a0.z*a0.z + a0.w*a0.w
             + a1.x*a1.x + a1.y*a1.y + a1.z*a1.z + a1.w*a1.w;
    float sj = b0.x*b0.x + b0.y*b0.y + b0.z*b0.z + b0.w*b0.w
             + b1.x*b1.x + b1.y*b1.y + b1.z*b1.z + b1.w*b1.w;
    #pragma unroll
    for (int o = 32; o; o >>= 1) {
      d += __shfl_xor(d, o); si += __shfl_xor(si, o); sj += __shfl_xor(sj, o);
    }
    if (lane == 0) nd[i] = sqrtf(fmaxf(si + sj - 2.0f * d, 1e-11f));
  }
}

// ---- K3: per-class gathered Gram, M-SPLIT: 2 blocks/class (r11 verbatim) -
__global__ __launch_bounds__(256) void k_cls(const u16* __restrict__ Fb,
    const float* __restrict__ sq, const float* __restrict__ nd,
    const int* __restrict__ cc, const int* __restrict__ pos,
    float* __restrict__ accf, float* __restrict__ out) {
  const int c = blockIdx.x >> 1, half = blockIdx.x & 1;
  __shared__ __align__(16) u16 P[128 * 512];     // 128 KB: full class tile
  __shared__ int posc[128];
  __shared__ float red[4];
  const int tid = threadIdx.x, wid = tid >> 6, lane = tid & 63;
  const int nc = cc[c];
  if (tid < 128) posc[tid] = pos[c * 128 + tid];
  __syncthreads();
  if (nc >= 2 && half * 64 < nc) {               // uniform branch per block
    const int wr = half, wc = wid;               // wave grid: 1 x 4
    const int r16 = lane & 15, gg = lane >> 4;
    const char* fb = (const char*)Fb;

    // stage: wave wid covers rows wid*32..wid*32+31; one instr = one row
    // (64 lanes x 16B). lane l -> LDS granule l, global granule l^(s&7).
    #pragma unroll 8
    for (int s = 0; s < 32; ++s) {
      const int row = wid * 32 + s;
      const int gr = posc[row];
      __builtin_amdgcn_global_load_lds(
          (const AS1 void*)(fb + (size_t)gr * 1024 + ((lane ^ (s & 7)) << 4)),
          (AS3 void*)(&P[row * 512]), 16, 0, 0);
    }

    f32x4 acc[4][2];
    #pragma unroll
    for (int m = 0; m < 4; ++m)
      #pragma unroll
      for (int n = 0; n < 2; ++n)
        #pragma unroll
        for (int q = 0; q < 4; ++q) acc[m][n][q] = 0.0f;

    __syncthreads();                             // one vmcnt(0) drain total
    #pragma unroll 4
    for (int t = 0; t < 16; ++t) {               // K = 16 x 32
      short8 af[4], bf[2];
      #pragma unroll
      for (int m = 0; m < 4; ++m) {
        const int row = wr * 64 + m * 16 + r16;
        const int gl = (t * 4 + gg) ^ (row & 7);
        af[m] = *(const short8*)&P[row * 512 + gl * 8];
      }
      #pragma unroll
      for (int n = 0; n < 2; ++n) {
        const int row = wc * 32 + n * 16 + r16;
        const int gl = (t * 4 + gg) ^ (row & 7);
        bf[n] = *(const short8*)&P[row * 512 + gl * 8];
      }
      #pragma unroll
      for (int m = 0; m < 4; ++m)
        #pragma unroll
        for (int n = 0; n < 2; ++n)
          acc[m][n] = __builtin_amdgcn_mfma_f32_16x16x32_bf16(af[m], bf[n], acc[m][n], 0, 0, 0);
    }

    // epilogue: hinge over valid (mi != nj, both < nc) ordered pairs
    float lsum = 0.0f;
    int njv[2]; float sqj[2];
    #pragma unroll
    for (int n = 0; n < 2; ++n) {
      const int nj = wc * 32 + n * 16 + r16;
      njv[n] = nj; sqj[n] = sq[posc[nj]];
    }
    #pragma unroll
    for (int m = 0; m < 4; ++m) {
      #pragma unroll
      for (int q = 0; q < 4; ++q) {
        const int mi = wr * 64 + m * 16 + gg * 4 + q;   // C/D: row=(lane>>4)*4+q
        const int i = posc[mi];
        const float sqi = sq[i], ndi = nd[i];
        const bool vi = mi < nc;
        #pragma unroll
        for (int n = 0; n < 2; ++n) {
          const float g = acc[m][n][q];
          const float dist = sqrtf(fmaxf(sqi + sqj[n] - 2.0f * g, 1e-11f));
          if (vi & (njv[n] < nc) & (mi != njv[n]))
            lsum += fmaxf(1.0f + dist - ndi, 0.0f);     // nd=inf -> 0 automatically
        }
      }
    }
    #pragma unroll
    for (int o = 32; o; o >>= 1) lsum += __shfl_xor(lsum, o);
    if (lane == 0) red[wid] = lsum;
    __syncthreads();
    if (tid == 0) atomicAdd(accf, red[0] + red[1] + red[2] + red[3]);
  }
  // pair-count (half 0 only) + last-block finalize (atomics only)
  if (tid == 0) {
    int* cnt  = (int*)accf + 1;
    int* done = (int*)accf + 2;
    if (half == 0 && nc < NN) atomicAdd(cnt, nc * (nc - 1));
    __threadfence();
    if (atomicAdd(done, 1) == 2 * NC - 1) {
      const float tot = atomicAdd(accf, 0.0f);    // atomic read
      const int n = atomicAdd(cnt, 0);            // atomic read
      out[0] = tot / (float)n;
    }
  }
}

extern "C" void kernel_launch(void* const* d_in, const int* in_sizes, int n_in,
                              void* d_out, int out_size, void* d_ws, size_t ws_size,
                              hipStream_t stream) {
  const float* F = (const float*)d_in[0];
  const int* labels = (const int*)d_in[1];   // harness materializes integers as int32
  const float* negu = (const float*)d_in[2];
  char* ws = (char*)d_ws;
  u16*   Fb    = (u16*)(ws + FB_OFF);
  float* sq    = (float*)(ws + SQ_OFF);
  float* nd    = (float*)(ws + ND_OFF);
  float* accf  = (float*)(ws + ACC_OFF);
  int*   cc    = (int*)(ws + CC_OFF);
  int*   pos   = (int*)(ws + POS_OFF);

  k_pos<<<NC,     256, 0, stream>>>(labels, cc, pos, (int*)accf);
  k_pn <<<4096,   256, 0, stream>>>(F, labels, negu, cc, pos, Fb, sq, nd);
  k_cls<<<2 * NC, 256, 0, stream>>>(Fb, sq, nd, cc, pos, accf, (float*)d_out);
}